// Round 7
// baseline (445.266 us; speedup 1.0000x reference)
//
#include <hip/hip_runtime.h>
#include <math.h>

typedef float f32x4 __attribute__((ext_vector_type(4)));

// Problem constants (from reference)
#define N_NODES 100000
#define C_CL 30
#define D_IN 256

// d_out float offsets: (out, mincut, ortho, Z, S) concatenated
#define OUT_MAT 0        // 30*64
#define OUT_MC 1920
#define OUT_OR 1921
#define OUT_Z 1922       // 30*256
#define OUT_S 9602       // N*30

// ws float offsets
#define WS_M 0           // 30*256  (M = S^T x)   [written by k_reduce]
#define WS_SS 7680       // 30*30
#define WS_CS 8580       // 30 (colsum S)
#define WS_CUT 8610      // 1  (zeroed by k_prep, atomic from k_edges)
#define WS_H1 8640       // 30*256
#define WS_WT4 24000     // 64*32 float4 = 8192 floats (W padded to 32 cols)
#define WS_S8 32256      // u8 S table: 1563*512 dwords = 3.2 MB (L2-resident)
#define WS_SLAB0 835584  // per-block partial slabs (after S8 end = 832512)

// slab layout (floats, per block): M 7680 | SS 900 | CS 30
#define SLAB_SS2 7680
#define SLAB_CS2 8580
#define SLAB_STRIDE2 8640
// R6: grid 512 left 270 blocks with TWO chunks (wall = 2x chunk latency,
// half the kernel at ~1 block/CU). One chunk per block: grid = NCHUNK.
#define MAX_R 782

#define CHUNK 128
#define NCHUNK ((N_NODES + CHUNK - 1) / CHUNK)   // 782

// ---------------------------------------------------------------------------
// prep: build WT4p[k4][c] (c padded to 32, cols 30/31 = 0); zero WS_CUT
__global__ __launch_bounds__(256)
void k_prep(const float* __restrict__ Wa, float* __restrict__ ws) {
  const int b = blockIdx.x, t = threadIdx.x;
  if (b < 8) {
    const int g = b * 256 + t;          // 0..2047 = 64 k4 * 32 c
    const int k4 = g >> 5, c = g & 31;
    float4 v = make_float4(0.f, 0.f, 0.f, 0.f);
    if (c < C_CL) {
      v.x = Wa[(4 * k4 + 0) * C_CL + c];
      v.y = Wa[(4 * k4 + 1) * C_CL + c];
      v.z = Wa[(4 * k4 + 2) * C_CL + c];
      v.w = Wa[(4 * k4 + 3) * C_CL + c];
    }
    reinterpret_cast<float4*>(ws + WS_WT4)[g] = v;
  } else {
    if (t == 0) ws[WS_CUT] = 0.f;
  }
}

// ---------------------------------------------------------------------------
// k_node v2 (proven R6): cooperative coalesced staging of x into LDS
// (8 k-slices, 8 lanes/row, each row fetched once per block), double-
// buffered, XOR-swizzled. Compute clusters via wave-uniform W reads.
__global__ __launch_bounds__(256, 4)
void k_node(const float* __restrict__ x, const float* __restrict__ wt4f,
            const float* __restrict__ ba, float* __restrict__ S_out,
            unsigned* __restrict__ S8) {
  __shared__ float lg[64][33];
  __shared__ float4 lx4[2][512];       // 2 x 64 rows x 8 chunks (16B) = 16 KB
  const int t = threadIdx.x;
  const int lane = t & 63;
  const int cg = __builtin_amdgcn_readfirstlane(t >> 6);   // wave-uniform 0..3
  const int node0 = blockIdx.x * 64;
  const int node = node0 + lane;
  const bool valid = (node < N_NODES);
  const float4* __restrict__ wt4 = reinterpret_cast<const float4*>(wt4f);

  // staging mapping: thread t covers rows (t>>3) and 32+(t>>3), chunk t&7
  const int srow = t >> 3;             // 0..31
  const int sch = t & 7;               // 16B chunk within slice
  const int ra = min(node0 + srow, N_NODES - 1);
  const int rb = min(node0 + 32 + srow, N_NODES - 1);
  const float* __restrict__ pa = x + (size_t)ra * 256 + sch * 4;
  const float* __restrict__ pb = x + (size_t)rb * 256 + sch * 4;
  // swizzled LDS float4 indices ( (32+srow)&7 == srow&7 -> wrb = wra + 256 )
  const int wra = srow * 8 + (sch ^ (srow & 7));
  const int wrb = wra + 256;
  const int lsw3 = lane & 7;           // compute-phase swizzle

  float acc[8];
  #pragma unroll
  for (int j = 0; j < 8; ++j) acc[j] = 0.f;

  // prologue: slice 0
  float4 va = *reinterpret_cast<const float4*>(pa);
  float4 vb = *reinterpret_cast<const float4*>(pb);
  lx4[0][wra] = va;
  lx4[0][wrb] = vb;
  __syncthreads();

  for (int s = 0; s < 8; ++s) {
    if (s < 7) {   // issue next-slice loads early (hide under FMA phase)
      va = *reinterpret_cast<const float4*>(pa + (s + 1) * 32);
      vb = *reinterpret_cast<const float4*>(pb + (s + 1) * 32);
    }
    const float4* __restrict__ lrow = &lx4[s & 1][lane * 8];
    #pragma unroll
    for (int c = 0; c < 8; ++c) {
      const float4 xv = lrow[c ^ lsw3];
      #pragma unroll
      for (int j = 0; j < 8; ++j) {
        const float4 wv = wt4[(s * 8 + c) * 32 + cg * 8 + j]; // scalar loads
        acc[j] += xv.x * wv.x + xv.y * wv.y + xv.z * wv.z + xv.w * wv.w;
      }
    }
    if (s < 7) {
      __syncthreads();                 // all waves done reading buf[(s+1)&1]
      lx4[(s + 1) & 1][wra] = va;
      lx4[(s + 1) & 1][wrb] = vb;
      __syncthreads();                 // writes visible before next compute
    }
  }

  #pragma unroll
  for (int j = 0; j < 8; ++j) lg[lane][cg * 8 + j] = acc[j];
  __syncthreads();

  // ---- softmax by wave 0 (reads combined logits from LDS) ----
  if (t < 64) {
    if (valid) {
      float v[C_CL];
      float mx = -3.0e38f;
      #pragma unroll
      for (int c = 0; c < C_CL; ++c) {
        v[c] = lg[t][c] + ba[c];
        mx = fmaxf(mx, v[c]);
      }
      float sm = 0.f;
      #pragma unroll
      for (int c = 0; c < C_CL; ++c) { v[c] = __expf(v[c] - mx); sm += v[c]; }
      const float r = 1.f / sm;
      #pragma unroll
      for (int c = 0; c < C_CL; ++c) lg[t][c] = v[c] * r;
    } else {
      #pragma unroll
      for (int c = 0; c < C_CL; ++c) lg[t][c] = 0.f;
    }
    lg[t][30] = 0.f; lg[t][31] = 0.f;
  }
  __syncthreads();

  // ---- outputs (256 threads) ----
  const int gbase = blockIdx.x * 1920;
  #pragma unroll
  for (int i = 0; i < 8; ++i) {
    const unsigned idx = i * 256 + t;
    if (idx < 1920u) {
      const unsigned n = idx / 30u, c = idx - 30u * n;
      const int g = gbase + (int)idx;
      if (g < N_NODES * C_CL) S_out[g] = lg[n][c];
    }
  }
  const unsigned sbase = (unsigned)blockIdx.x * 512;
  #pragma unroll
  for (int i = 0; i < 2; ++i) {
    const unsigned idx = i * 256 + t;            // 0..511
    const unsigned n = idx >> 3, j = idx & 7;
    const unsigned b0 = (unsigned)(lg[n][j * 4 + 0] * 255.f + 0.5f);
    const unsigned b1 = (unsigned)(lg[n][j * 4 + 1] * 255.f + 0.5f);
    const unsigned b2 = (unsigned)(lg[n][j * 4 + 2] * 255.f + 0.5f);
    const unsigned b3 = (unsigned)(lg[n][j * 4 + 3] * 255.f + 0.5f);
    S8[sbase + idx] = b0 | (b1 << 8) | (b2 << 16) | (b3 << 24);
  }
}

// ---------------------------------------------------------------------------
// cut = sum_e dot(S[r], S[c]); u8 rows (32 B, table 3.2 MB, L2-hot right
// after k_node). One edge per thread pass; exact integer dot, scale once.
__device__ __forceinline__ int dd(unsigned a, unsigned b, int acc) {
  acc += (int)((a & 0xffu) * (b & 0xffu));
  acc += (int)(((a >> 8) & 0xffu) * ((b >> 8) & 0xffu));
  acc += (int)(((a >> 16) & 0xffu) * ((b >> 16) & 0xffu));
  acc += (int)((a >> 24) * (b >> 24));
  return acc;
}

__global__ __launch_bounds__(256)
void k_edges(const int* __restrict__ ei, const int E,
             const unsigned* __restrict__ S8, float* __restrict__ ws) {
  const int t = threadIdx.x;
  const int tid = blockIdx.x * 256 + t;
  const int* __restrict__ row = ei;
  const int* __restrict__ col = ei + E;
  float acc = 0.f;
  for (int e = tid; e < E; e += gridDim.x * 256) {
    const int r = row[e], c = col[e];
    const uint4* pr = reinterpret_cast<const uint4*>(S8 + (size_t)r * 8);
    const uint4* pc = reinterpret_cast<const uint4*>(S8 + (size_t)c * 8);
    const uint4 a0 = pr[0], a1 = pr[1];
    const uint4 b0 = pc[0], b1 = pc[1];
    int s = 0;
    s = dd(a0.x, b0.x, s); s = dd(a0.y, b0.y, s);
    s = dd(a0.z, b0.z, s); s = dd(a0.w, b0.w, s);
    s = dd(a1.x, b1.x, s); s = dd(a1.y, b1.y, s);
    s = dd(a1.z, b1.z, s); s = dd(a1.w, b1.w, s);
    acc += (float)s;
  }
  acc *= (1.f / 65025.f);     // (1/255)^2
  #pragma unroll
  for (int m = 1; m < 64; m <<= 1) acc += __shfl_xor(acc, m, 64);
  __shared__ float wsum[4];
  if ((t & 63) == 0) wsum[t >> 6] = acc;
  __syncthreads();
  if (t == 0)
    atomicAdd(&ws[WS_CUT], wsum[0] + wsum[1] + wsum[2] + wsum[3]);
}

// ---------------------------------------------------------------------------
// M = S^T x (+ SS = S^T S, colsum). ONE 128-node chunk per block (grid =
// NCHUNK), persistent register accumulators, per-block slab output.
__global__ __launch_bounds__(256, 2)
void k_M2(const float* __restrict__ x, const float* __restrict__ Sp,
          float* __restrict__ slabs, const int R) {
  __shared__ float sraw[8192];                 // 32 KB, dual-use
  float (*sm)[32] = reinterpret_cast<float (*)[32]>(sraw);
  const int t = threadIdx.x;
  const int h = t >> 7, sub = (t >> 6) & 1, lc = t & 63;  // M layout
  const int i4 = (t >> 3) & 7, j4 = t & 7, w = t >> 6;    // SS layout
  const f32x4* __restrict__ x4 = reinterpret_cast<const f32x4*>(x);

  float a[16][4];
  #pragma unroll
  for (int j = 0; j < 16; ++j) { a[j][0] = 0.f; a[j][1] = 0.f; a[j][2] = 0.f; a[j][3] = 0.f; }
  float ssq[16];
  #pragma unroll
  for (int j = 0; j < 16; ++j) ssq[j] = 0.f;
  float cs = 0.f;

  for (int chunk = blockIdx.x; chunk < NCHUNK; chunk += R) {
    const int node0 = chunk * CHUNK;
    const int rows_valid = N_NODES - node0;
    __syncthreads();
    #pragma unroll
    for (int i = 0; i < 15; ++i) {
      const int idx = i * 256 + t;
      const int n = idx / 30, c = idx - 30 * n;
      const int g = node0 * C_CL + idx;
      sm[n][c] = (g < N_NODES * C_CL) ? Sp[g] : 0.f;
    }
    sm[t & 127][30 + (t >> 7)] = 0.f;
    __syncthreads();

    if (rows_valid >= CHUNK) {
      #pragma unroll 4
      for (int n = 0; n < 64; ++n) {
        const int nn = sub * 64 + n;
        const f32x4 xv = __builtin_nontemporal_load(&x4[(size_t)(node0 + nn) * 64 + lc]);
        const float4 s0 = *reinterpret_cast<const float4*>(&sm[nn][h * 16 + 0]);
        const float4 s1 = *reinterpret_cast<const float4*>(&sm[nn][h * 16 + 4]);
        const float4 s2 = *reinterpret_cast<const float4*>(&sm[nn][h * 16 + 8]);
        const float4 s3 = *reinterpret_cast<const float4*>(&sm[nn][h * 16 + 12]);
        const float sv[16] = {s0.x, s0.y, s0.z, s0.w, s1.x, s1.y, s1.z, s1.w,
                              s2.x, s2.y, s2.z, s2.w, s3.x, s3.y, s3.z, s3.w};
        #pragma unroll
        for (int j = 0; j < 16; ++j) {
          a[j][0] += sv[j] * xv.x; a[j][1] += sv[j] * xv.y;
          a[j][2] += sv[j] * xv.z; a[j][3] += sv[j] * xv.w;
        }
      }
    } else {
      for (int n = 0; n < 64; ++n) {
        const int nn = sub * 64 + n;
        f32x4 xv = (f32x4)0.f;
        if (nn < rows_valid) xv = x4[(size_t)(node0 + nn) * 64 + lc];
        const float4 s0 = *reinterpret_cast<const float4*>(&sm[nn][h * 16 + 0]);
        const float4 s1 = *reinterpret_cast<const float4*>(&sm[nn][h * 16 + 4]);
        const float4 s2 = *reinterpret_cast<const float4*>(&sm[nn][h * 16 + 8]);
        const float4 s3 = *reinterpret_cast<const float4*>(&sm[nn][h * 16 + 12]);
        const float sv[16] = {s0.x, s0.y, s0.z, s0.w, s1.x, s1.y, s1.z, s1.w,
                              s2.x, s2.y, s2.z, s2.w, s3.x, s3.y, s3.z, s3.w};
        #pragma unroll
        for (int j = 0; j < 16; ++j) {
          a[j][0] += sv[j] * xv.x; a[j][1] += sv[j] * xv.y;
          a[j][2] += sv[j] * xv.z; a[j][3] += sv[j] * xv.w;
        }
      }
    }

    #pragma unroll 4
    for (int n = 0; n < 32; ++n) {
      const int nn = w * 32 + n;
      const float4 av = *reinterpret_cast<const float4*>(&sm[nn][i4 * 4]);
      const float4 bv = *reinterpret_cast<const float4*>(&sm[nn][j4 * 4]);
      const float af[4] = {av.x, av.y, av.z, av.w};
      const float bf[4] = {bv.x, bv.y, bv.z, bv.w};
      #pragma unroll
      for (int ii = 0; ii < 4; ++ii)
        #pragma unroll
        for (int jj = 0; jj < 4; ++jj) ssq[ii * 4 + jj] += af[ii] * bf[jj];
    }
    if (t < C_CL) {
      #pragma unroll 4
      for (int n = 0; n < CHUNK; ++n) cs += sm[n][t];
    }
  }

  // ---- flush to private slab (plain stores; zero contention) ----
  float* __restrict__ slab = slabs + (size_t)blockIdx.x * SLAB_STRIDE2;
  __syncthreads();
  if (sub == 1) {
    #pragma unroll
    for (int j = 0; j < 16; ++j) {
      const int c = h * 16 + j;
      if (c < C_CL) {
        #pragma unroll
        for (int q = 0; q < 4; ++q) sraw[c * 256 + lc * 4 + q] = a[j][q];
      }
    }
  }
  __syncthreads();
  if (sub == 0) {
    #pragma unroll
    for (int j = 0; j < 16; ++j) {
      const int c = h * 16 + j;
      if (c < C_CL) {
        #pragma unroll
        for (int q = 0; q < 4; ++q)
          slab[c * 256 + lc * 4 + q] = a[j][q] + sraw[c * 256 + lc * 4 + q];
      }
    }
  }
  // ---- SS: combine 4 wave-partials in LDS, write single 900 block ----
  __syncthreads();
  #pragma unroll
  for (int ii = 0; ii < 4; ++ii) {
    #pragma unroll
    for (int jj = 0; jj < 4; ++jj) {
      const int gi = i4 * 4 + ii, gj = j4 * 4 + jj;
      if (gi < C_CL && gj < C_CL)
        sraw[w * 900 + gi * C_CL + gj] = ssq[ii * 4 + jj];
    }
  }
  __syncthreads();
  for (int q = t; q < 900; q += 256)
    slab[SLAB_SS2 + q] = (sraw[q] + sraw[900 + q]) + (sraw[1800 + q] + sraw[2700 + q]);
  if (t < C_CL) slab[SLAB_CS2 + t] = cs;
}

// ---------------------------------------------------------------------------
// Single-stage reduce: ws[i] = sum_r slabs[r][i] (coalesced across i).
__global__ __launch_bounds__(256)
void k_reduce(const float* __restrict__ slabs, const int R,
              float* __restrict__ ws) {
  const int i = blockIdx.x * 256 + threadIdx.x;
  if (i >= 8610) return;
  float s = 0.f;
  int r = 0;
  for (; r + 16 <= R; r += 16) {
    const float* p = slabs + (size_t)r * SLAB_STRIDE2 + i;
    float v[16];
    #pragma unroll
    for (int q = 0; q < 16; ++q) v[q] = p[(size_t)q * SLAB_STRIDE2];
    float s0 = ((v[0] + v[1]) + (v[2] + v[3])) + ((v[4] + v[5]) + (v[6] + v[7]));
    float s1 = ((v[8] + v[9]) + (v[10] + v[11])) + ((v[12] + v[13]) + (v[14] + v[15]));
    s += s0 + s1;
  }
  for (; r < R; ++r) s += slabs[(size_t)r * SLAB_STRIDE2 + i];
  ws[i] = s;
}

// ---------------------------------------------------------------------------
// kZ1 = Z + first Shapley layer, fused via
//   colsum(Z) = colsum(M)@Wp + (sum CS)*bp   (row-independent)
__global__ __launch_bounds__(256)
void k_z1(const float* __restrict__ ws, const float* __restrict__ Wp,
          const float* __restrict__ bp, const float* __restrict__ W1,
          float* __restrict__ out, float* __restrict__ h1out) {
  __shared__ float Mr[256], Mc[256], sh[256];
  const int r = blockIdx.x, t = threadIdx.x;
  float mc = 0.f;
  #pragma unroll
  for (int rr = 0; rr < C_CL; ++rr) mc += ws[WS_M + rr * 256 + t];
  Mc[t] = mc;
  Mr[t] = ws[WS_M + r * 256 + t];
  float scs = 0.f;
  #pragma unroll
  for (int rr = 0; rr < C_CL; ++rr) scs += ws[WS_CS + rr];
  __syncthreads();
  const float bpt = bp[t];
  float az = ws[WS_CS + r] * bpt;   // Z row r, col t
  float ac = scs * bpt;             // colsum(Z) col t
  #pragma unroll 8
  for (int k = 0; k < 256; ++k) {
    const float wv = Wp[(size_t)k * 256 + t];
    az += Mr[k] * wv;
    ac += Mc[k] * wv;
  }
  out[OUT_Z + r * 256 + t] = az;
  sh[t] = az + (1.f / 30.f) * ac;
  __syncthreads();
  float a1 = 0.f;
  #pragma unroll 8
  for (int k = 0; k < 256; ++k) a1 += sh[k] * W1[(size_t)k * 256 + t];
  h1out[r * 256 + t] = fmaxf(a1, 0.f);
}

// ---------------------------------------------------------------------------
// kZ2 = second Shapley layer + output head; block 30: mincut + ortho scalars
__global__ __launch_bounds__(256)
void k_z2(const float* __restrict__ ws, const float* __restrict__ W2,
          const float* __restrict__ Wo, const float* __restrict__ bo,
          float* __restrict__ out, const float vol) {
  __shared__ float sh[256];
  __shared__ float h2[256];
  __shared__ float red[4][64];
  __shared__ float wsum[4];
  const int r = blockIdx.x, t = threadIdx.x;
  if (r < C_CL) {
    float cs1 = 0.f;
    #pragma unroll
    for (int rr = 0; rr < C_CL; ++rr) cs1 += ws[WS_H1 + rr * 256 + t];
    sh[t] = ws[WS_H1 + r * 256 + t] + (1.f / 30.f) * cs1;
    __syncthreads();
    float a2 = 0.f;
    #pragma unroll 8
    for (int k = 0; k < 256; ++k) a2 += sh[k] * W2[(size_t)k * 256 + t];
    h2[t] = fmaxf(a2, 0.f);
    __syncthreads();
    const int c = t & 63, q = t >> 6;
    float ao = 0.f;
    #pragma unroll 8
    for (int k = q * 64; k < q * 64 + 64; ++k) ao += h2[k] * Wo[k * 64 + c];
    red[q][c] = ao;
    __syncthreads();
    if (t < 64)
      out[OUT_MAT + r * 64 + t] =
          bo[t] + ((red[0][t] + red[1][t]) + (red[2][t] + red[3][t]));
  } else {
    float s = 0.f;
    for (int i = t; i < 900; i += 256) {
      const float d = ws[WS_SS + i] - ((i / C_CL == i % C_CL) ? 1.f : 0.f);
      s += d * d;
    }
    #pragma unroll
    for (int m = 1; m < 64; m <<= 1) s += __shfl_xor(s, m, 64);
    if ((t & 63) == 0) wsum[t >> 6] = s;
    __syncthreads();
    if (t == 0) {
      out[OUT_OR] = sqrtf(wsum[0] + wsum[1] + wsum[2] + wsum[3]);
      out[OUT_MC] = -ws[WS_CUT] / (vol + 1e-9f);
    }
  }
}

// ---------------------------------------------------------------------------
extern "C" void kernel_launch(void* const* d_in, const int* in_sizes, int n_in,
                              void* d_out, int out_size, void* d_ws, size_t ws_size,
                              hipStream_t stream) {
  (void)n_in; (void)out_size;
  const float* x  = (const float*)d_in[0];
  const int*   ei = (const int*)d_in[1];
  const float* Wa = (const float*)d_in[2];
  const float* ba = (const float*)d_in[3];
  const float* Wp = (const float*)d_in[4];
  const float* bp = (const float*)d_in[5];
  const float* W1 = (const float*)d_in[6];
  const float* W2 = (const float*)d_in[7];
  const float* Wo = (const float*)d_in[8];
  const float* bo = (const float*)d_in[9];
  float* out = (float*)d_out;
  float* ws  = (float*)d_ws;
  unsigned* S8 = (unsigned*)(ws + WS_S8);
  float* slabs = ws + WS_SLAB0;
  const int E = in_sizes[1] / 2;

  long avail = (long)(ws_size / 4) - WS_SLAB0;
  int R = (int)(avail / SLAB_STRIDE2);
  if (R > MAX_R) R = MAX_R;
  if (R < 1) R = 1;

  k_prep<<<9, 256, 0, stream>>>(Wa, ws);
  k_node<<<1563, 256, 0, stream>>>(x, ws + WS_WT4, ba, out + OUT_S, S8);
  k_edges<<<4096, 256, 0, stream>>>(ei, E, S8, ws);
  k_M2<<<R, 256, 0, stream>>>(x, out + OUT_S, slabs, R);
  k_reduce<<<34, 256, 0, stream>>>(slabs, R, ws);
  k_z1<<<C_CL, 256, 0, stream>>>(ws, Wp, bp, W1, out, ws + WS_H1);
  k_z2<<<C_CL + 1, 256, 0, stream>>>(ws, W2, Wo, bo, out, (float)E);
}

// Round 8
// 400.252 us; speedup vs baseline: 1.1125x; 1.1125x over previous
//
#include <hip/hip_runtime.h>
#include <math.h>

typedef float f32x4 __attribute__((ext_vector_type(4)));

// Problem constants (from reference)
#define N_NODES 100000
#define C_CL 30
#define D_IN 256

// d_out float offsets: (out, mincut, ortho, Z, S) concatenated
#define OUT_MAT 0        // 30*64
#define OUT_MC 1920
#define OUT_OR 1921
#define OUT_Z 1922       // 30*256
#define OUT_S 9602       // N*30

// ws float offsets
#define WS_M 0           // 30*256  (M = S^T x)   [written by k_reduce]
#define WS_SS 7680       // 30*30
#define WS_CS 8580       // 30 (colsum S)
#define WS_CUT 8610      // 1  (zeroed by k_prep, atomic from k_edges)
#define WS_H1 8640       // 30*256
#define WS_WT4 24000     // 64*32 float4 = 8192 floats (W padded to 32 cols)
#define WS_S8 32256      // u8 S table: 1563*512 dwords = 3.2 MB (L2-resident)
#define WS_SLAB0 835584  // per-block partial slabs (after S8 end = 832512)

// slab layout (floats, per block): M 7680 | SS 900 | CS 30
#define SLAB_SS2 7680
#define SLAB_CS2 8580
#define SLAB_STRIDE2 8640
// R7 lesson: grid 782 changed nothing in k_M2 and inflated reduce traffic.
// Back to the 421us configuration.
#define MAX_R 512

#define CHUNK 128
#define NCHUNK ((N_NODES + CHUNK - 1) / CHUNK)   // 782

// ---------------------------------------------------------------------------
// prep: build WT4p[k4][c] (c padded to 32, cols 30/31 = 0); zero WS_CUT
__global__ __launch_bounds__(256)
void k_prep(const float* __restrict__ Wa, float* __restrict__ ws) {
  const int b = blockIdx.x, t = threadIdx.x;
  if (b < 8) {
    const int g = b * 256 + t;          // 0..2047 = 64 k4 * 32 c
    const int k4 = g >> 5, c = g & 31;
    float4 v = make_float4(0.f, 0.f, 0.f, 0.f);
    if (c < C_CL) {
      v.x = Wa[(4 * k4 + 0) * C_CL + c];
      v.y = Wa[(4 * k4 + 1) * C_CL + c];
      v.z = Wa[(4 * k4 + 2) * C_CL + c];
      v.w = Wa[(4 * k4 + 3) * C_CL + c];
    }
    reinterpret_cast<float4*>(ws + WS_WT4)[g] = v;
  } else {
    if (t == 0) ws[WS_CUT] = 0.f;
  }
}

// ---------------------------------------------------------------------------
// k_node v2 (proven R6): cooperative coalesced staging of x into LDS
// (8 k-slices, 8 lanes/row, each row fetched once per block), double-
// buffered, XOR-swizzled. Compute clusters via wave-uniform W reads.
__global__ __launch_bounds__(256, 4)
void k_node(const float* __restrict__ x, const float* __restrict__ wt4f,
            const float* __restrict__ ba, float* __restrict__ S_out,
            unsigned* __restrict__ S8) {
  __shared__ float lg[64][33];
  __shared__ float4 lx4[2][512];       // 2 x 64 rows x 8 chunks (16B) = 16 KB
  const int t = threadIdx.x;
  const int lane = t & 63;
  const int cg = __builtin_amdgcn_readfirstlane(t >> 6);   // wave-uniform 0..3
  const int node0 = blockIdx.x * 64;
  const int node = node0 + lane;
  const bool valid = (node < N_NODES);
  const float4* __restrict__ wt4 = reinterpret_cast<const float4*>(wt4f);

  // staging mapping: thread t covers rows (t>>3) and 32+(t>>3), chunk t&7
  const int srow = t >> 3;             // 0..31
  const int sch = t & 7;               // 16B chunk within slice
  const int ra = min(node0 + srow, N_NODES - 1);
  const int rb = min(node0 + 32 + srow, N_NODES - 1);
  const float* __restrict__ pa = x + (size_t)ra * 256 + sch * 4;
  const float* __restrict__ pb = x + (size_t)rb * 256 + sch * 4;
  // swizzled LDS float4 indices ( (32+srow)&7 == srow&7 -> wrb = wra + 256 )
  const int wra = srow * 8 + (sch ^ (srow & 7));
  const int wrb = wra + 256;
  const int lsw3 = lane & 7;           // compute-phase swizzle

  float acc[8];
  #pragma unroll
  for (int j = 0; j < 8; ++j) acc[j] = 0.f;

  // prologue: slice 0
  float4 va = *reinterpret_cast<const float4*>(pa);
  float4 vb = *reinterpret_cast<const float4*>(pb);
  lx4[0][wra] = va;
  lx4[0][wrb] = vb;
  __syncthreads();

  for (int s = 0; s < 8; ++s) {
    if (s < 7) {   // issue next-slice loads early (hide under FMA phase)
      va = *reinterpret_cast<const float4*>(pa + (s + 1) * 32);
      vb = *reinterpret_cast<const float4*>(pb + (s + 1) * 32);
    }
    const float4* __restrict__ lrow = &lx4[s & 1][lane * 8];
    #pragma unroll
    for (int c = 0; c < 8; ++c) {
      const float4 xv = lrow[c ^ lsw3];
      #pragma unroll
      for (int j = 0; j < 8; ++j) {
        const float4 wv = wt4[(s * 8 + c) * 32 + cg * 8 + j]; // scalar loads
        acc[j] += xv.x * wv.x + xv.y * wv.y + xv.z * wv.z + xv.w * wv.w;
      }
    }
    if (s < 7) {
      __syncthreads();                 // all waves done reading buf[(s+1)&1]
      lx4[(s + 1) & 1][wra] = va;
      lx4[(s + 1) & 1][wrb] = vb;
      __syncthreads();                 // writes visible before next compute
    }
  }

  #pragma unroll
  for (int j = 0; j < 8; ++j) lg[lane][cg * 8 + j] = acc[j];
  __syncthreads();

  // ---- softmax by wave 0 (reads combined logits from LDS) ----
  if (t < 64) {
    if (valid) {
      float v[C_CL];
      float mx = -3.0e38f;
      #pragma unroll
      for (int c = 0; c < C_CL; ++c) {
        v[c] = lg[t][c] + ba[c];
        mx = fmaxf(mx, v[c]);
      }
      float sm = 0.f;
      #pragma unroll
      for (int c = 0; c < C_CL; ++c) { v[c] = __expf(v[c] - mx); sm += v[c]; }
      const float r = 1.f / sm;
      #pragma unroll
      for (int c = 0; c < C_CL; ++c) lg[t][c] = v[c] * r;
    } else {
      #pragma unroll
      for (int c = 0; c < C_CL; ++c) lg[t][c] = 0.f;
    }
    lg[t][30] = 0.f; lg[t][31] = 0.f;
  }
  __syncthreads();

  // ---- outputs (256 threads) ----
  const int gbase = blockIdx.x * 1920;
  #pragma unroll
  for (int i = 0; i < 8; ++i) {
    const unsigned idx = i * 256 + t;
    if (idx < 1920u) {
      const unsigned n = idx / 30u, c = idx - 30u * n;
      const int g = gbase + (int)idx;
      if (g < N_NODES * C_CL) S_out[g] = lg[n][c];
    }
  }
  const unsigned sbase = (unsigned)blockIdx.x * 512;
  #pragma unroll
  for (int i = 0; i < 2; ++i) {
    const unsigned idx = i * 256 + t;            // 0..511
    const unsigned n = idx >> 3, j = idx & 7;
    const unsigned b0 = (unsigned)(lg[n][j * 4 + 0] * 255.f + 0.5f);
    const unsigned b1 = (unsigned)(lg[n][j * 4 + 1] * 255.f + 0.5f);
    const unsigned b2 = (unsigned)(lg[n][j * 4 + 2] * 255.f + 0.5f);
    const unsigned b3 = (unsigned)(lg[n][j * 4 + 3] * 255.f + 0.5f);
    S8[sbase + idx] = b0 | (b1 << 8) | (b2 << 16) | (b3 << 24);
  }
}

// ---------------------------------------------------------------------------
// cut = sum_e dot(S[r], S[c]); u8 rows (32 B, table 3.2 MB, L2-hot right
// after k_node). One edge per thread pass; exact integer dot, scale once.
__device__ __forceinline__ int dd(unsigned a, unsigned b, int acc) {
  acc += (int)((a & 0xffu) * (b & 0xffu));
  acc += (int)(((a >> 8) & 0xffu) * ((b >> 8) & 0xffu));
  acc += (int)(((a >> 16) & 0xffu) * ((b >> 16) & 0xffu));
  acc += (int)((a >> 24) * (b >> 24));
  return acc;
}

__global__ __launch_bounds__(256)
void k_edges(const int* __restrict__ ei, const int E,
             const unsigned* __restrict__ S8, float* __restrict__ ws) {
  const int t = threadIdx.x;
  const int tid = blockIdx.x * 256 + t;
  const int* __restrict__ row = ei;
  const int* __restrict__ col = ei + E;
  float acc = 0.f;
  for (int e = tid; e < E; e += gridDim.x * 256) {
    const int r = row[e], c = col[e];
    const uint4* pr = reinterpret_cast<const uint4*>(S8 + (size_t)r * 8);
    const uint4* pc = reinterpret_cast<const uint4*>(S8 + (size_t)c * 8);
    const uint4 a0 = pr[0], a1 = pr[1];
    const uint4 b0 = pc[0], b1 = pc[1];
    int s = 0;
    s = dd(a0.x, b0.x, s); s = dd(a0.y, b0.y, s);
    s = dd(a0.z, b0.z, s); s = dd(a0.w, b0.w, s);
    s = dd(a1.x, b1.x, s); s = dd(a1.y, b1.y, s);
    s = dd(a1.z, b1.z, s); s = dd(a1.w, b1.w, s);
    acc += (float)s;
  }
  acc *= (1.f / 65025.f);     // (1/255)^2
  #pragma unroll
  for (int m = 1; m < 64; m <<= 1) acc += __shfl_xor(acc, m, 64);
  __shared__ float wsum[4];
  if ((t & 63) == 0) wsum[t >> 6] = acc;
  __syncthreads();
  if (t == 0)
    atomicAdd(&ws[WS_CUT], wsum[0] + wsum[1] + wsum[2] + wsum[3]);
}

// ---------------------------------------------------------------------------
// M = S^T x (+ SS = S^T S, colsum). Grid-stride over 128-node chunks.
// R8: software-pipelined x stream — group g+1's 4 row-loads are issued
// BEFORE group g's FMAs (load->use distance = one group of compute,
// ~730 cy, covering L2 and most HBM latency). Plain loads (no nt) so the
// wave-pairs (0/2, 1/3) reading the same rows dedup in L1.
__global__ __launch_bounds__(256, 2)
void k_M2(const float* __restrict__ x, const float* __restrict__ Sp,
          float* __restrict__ slabs, const int R) {
  __shared__ float sraw[8192];                 // 32 KB, dual-use
  float (*sm)[32] = reinterpret_cast<float (*)[32]>(sraw);
  const int t = threadIdx.x;
  const int h = t >> 7, sub = (t >> 6) & 1, lc = t & 63;  // M layout
  const int i4 = (t >> 3) & 7, j4 = t & 7, w = t >> 6;    // SS layout
  const f32x4* __restrict__ x4 = reinterpret_cast<const f32x4*>(x);

  float a[16][4];
  #pragma unroll
  for (int j = 0; j < 16; ++j) { a[j][0] = 0.f; a[j][1] = 0.f; a[j][2] = 0.f; a[j][3] = 0.f; }
  float ssq[16];
  #pragma unroll
  for (int j = 0; j < 16; ++j) ssq[j] = 0.f;
  float cs = 0.f;

  for (int chunk = blockIdx.x; chunk < NCHUNK; chunk += R) {
    const int node0 = chunk * CHUNK;
    const int rows_valid = N_NODES - node0;
    __syncthreads();
    #pragma unroll
    for (int i = 0; i < 15; ++i) {
      const int idx = i * 256 + t;
      const int n = idx / 30, c = idx - 30 * n;
      const int g = node0 * C_CL + idx;
      sm[n][c] = (g < N_NODES * C_CL) ? Sp[g] : 0.f;
    }
    sm[t & 127][30 + (t >> 7)] = 0.f;
    __syncthreads();

    if (rows_valid >= CHUNK) {
      // software-pipelined: 16 groups of 4 rows; prefetch next group first
      const f32x4* __restrict__ xb =
          &x4[((size_t)node0 + sub * 64) * 64 + lc];
      f32x4 p0 = xb[0], p1 = xb[64], p2 = xb[128], p3 = xb[192];
      #pragma unroll 1
      for (int g = 0; g < 16; ++g) {
        const f32x4 c0 = p0, c1 = p1, c2 = p2, c3 = p3;
        if (g < 15) {
          const f32x4* __restrict__ nxt = xb + (size_t)(g + 1) * 256;
          p0 = nxt[0]; p1 = nxt[64]; p2 = nxt[128]; p3 = nxt[192];
        }
        const int nb = sub * 64 + g * 4;
        #pragma unroll
        for (int i = 0; i < 4; ++i) {
          const int nn = nb + i;
          const f32x4 xv = (i == 0) ? c0 : (i == 1) ? c1 : (i == 2) ? c2 : c3;
          const float4 s0 = *reinterpret_cast<const float4*>(&sm[nn][h * 16 + 0]);
          const float4 s1 = *reinterpret_cast<const float4*>(&sm[nn][h * 16 + 4]);
          const float4 s2 = *reinterpret_cast<const float4*>(&sm[nn][h * 16 + 8]);
          const float4 s3 = *reinterpret_cast<const float4*>(&sm[nn][h * 16 + 12]);
          const float sv[16] = {s0.x, s0.y, s0.z, s0.w, s1.x, s1.y, s1.z, s1.w,
                                s2.x, s2.y, s2.z, s2.w, s3.x, s3.y, s3.z, s3.w};
          #pragma unroll
          for (int j = 0; j < 16; ++j) {
            a[j][0] += sv[j] * xv.x; a[j][1] += sv[j] * xv.y;
            a[j][2] += sv[j] * xv.z; a[j][3] += sv[j] * xv.w;
          }
        }
      }
    } else {
      for (int n = 0; n < 64; ++n) {
        const int nn = sub * 64 + n;
        f32x4 xv = (f32x4)0.f;
        if (nn < rows_valid) xv = x4[(size_t)(node0 + nn) * 64 + lc];
        const float4 s0 = *reinterpret_cast<const float4*>(&sm[nn][h * 16 + 0]);
        const float4 s1 = *reinterpret_cast<const float4*>(&sm[nn][h * 16 + 4]);
        const float4 s2 = *reinterpret_cast<const float4*>(&sm[nn][h * 16 + 8]);
        const float4 s3 = *reinterpret_cast<const float4*>(&sm[nn][h * 16 + 12]);
        const float sv[16] = {s0.x, s0.y, s0.z, s0.w, s1.x, s1.y, s1.z, s1.w,
                              s2.x, s2.y, s2.z, s2.w, s3.x, s3.y, s3.z, s3.w};
        #pragma unroll
        for (int j = 0; j < 16; ++j) {
          a[j][0] += sv[j] * xv.x; a[j][1] += sv[j] * xv.y;
          a[j][2] += sv[j] * xv.z; a[j][3] += sv[j] * xv.w;
        }
      }
    }

    #pragma unroll 4
    for (int n = 0; n < 32; ++n) {
      const int nn = w * 32 + n;
      const float4 av = *reinterpret_cast<const float4*>(&sm[nn][i4 * 4]);
      const float4 bv = *reinterpret_cast<const float4*>(&sm[nn][j4 * 4]);
      const float af[4] = {av.x, av.y, av.z, av.w};
      const float bf[4] = {bv.x, bv.y, bv.z, bv.w};
      #pragma unroll
      for (int ii = 0; ii < 4; ++ii)
        #pragma unroll
        for (int jj = 0; jj < 4; ++jj) ssq[ii * 4 + jj] += af[ii] * bf[jj];
    }
    if (t < C_CL) {
      #pragma unroll 4
      for (int n = 0; n < CHUNK; ++n) cs += sm[n][t];
    }
  }

  // ---- flush to private slab (plain stores; zero contention) ----
  float* __restrict__ slab = slabs + (size_t)blockIdx.x * SLAB_STRIDE2;
  __syncthreads();
  if (sub == 1) {
    #pragma unroll
    for (int j = 0; j < 16; ++j) {
      const int c = h * 16 + j;
      if (c < C_CL) {
        #pragma unroll
        for (int q = 0; q < 4; ++q) sraw[c * 256 + lc * 4 + q] = a[j][q];
      }
    }
  }
  __syncthreads();
  if (sub == 0) {
    #pragma unroll
    for (int j = 0; j < 16; ++j) {
      const int c = h * 16 + j;
      if (c < C_CL) {
        #pragma unroll
        for (int q = 0; q < 4; ++q)
          slab[c * 256 + lc * 4 + q] = a[j][q] + sraw[c * 256 + lc * 4 + q];
      }
    }
  }
  // ---- SS: combine 4 wave-partials in LDS, write single 900 block ----
  __syncthreads();
  #pragma unroll
  for (int ii = 0; ii < 4; ++ii) {
    #pragma unroll
    for (int jj = 0; jj < 4; ++jj) {
      const int gi = i4 * 4 + ii, gj = j4 * 4 + jj;
      if (gi < C_CL && gj < C_CL)
        sraw[w * 900 + gi * C_CL + gj] = ssq[ii * 4 + jj];
    }
  }
  __syncthreads();
  for (int q = t; q < 900; q += 256)
    slab[SLAB_SS2 + q] = (sraw[q] + sraw[900 + q]) + (sraw[1800 + q] + sraw[2700 + q]);
  if (t < C_CL) slab[SLAB_CS2 + t] = cs;
}

// ---------------------------------------------------------------------------
// Single-stage reduce: ws[i] = sum_r slabs[r][i] (coalesced across i).
__global__ __launch_bounds__(256)
void k_reduce(const float* __restrict__ slabs, const int R,
              float* __restrict__ ws) {
  const int i = blockIdx.x * 256 + threadIdx.x;
  if (i >= 8610) return;
  float s = 0.f;
  int r = 0;
  for (; r + 16 <= R; r += 16) {
    const float* p = slabs + (size_t)r * SLAB_STRIDE2 + i;
    float v[16];
    #pragma unroll
    for (int q = 0; q < 16; ++q) v[q] = p[(size_t)q * SLAB_STRIDE2];
    float s0 = ((v[0] + v[1]) + (v[2] + v[3])) + ((v[4] + v[5]) + (v[6] + v[7]));
    float s1 = ((v[8] + v[9]) + (v[10] + v[11])) + ((v[12] + v[13]) + (v[14] + v[15]));
    s += s0 + s1;
  }
  for (; r < R; ++r) s += slabs[(size_t)r * SLAB_STRIDE2 + i];
  ws[i] = s;
}

// ---------------------------------------------------------------------------
// kZ1 = Z + first Shapley layer, fused via
//   colsum(Z) = colsum(M)@Wp + (sum CS)*bp   (row-independent)
__global__ __launch_bounds__(256)
void k_z1(const float* __restrict__ ws, const float* __restrict__ Wp,
          const float* __restrict__ bp, const float* __restrict__ W1,
          float* __restrict__ out, float* __restrict__ h1out) {
  __shared__ float Mr[256], Mc[256], sh[256];
  const int r = blockIdx.x, t = threadIdx.x;
  float mc = 0.f;
  #pragma unroll
  for (int rr = 0; rr < C_CL; ++rr) mc += ws[WS_M + rr * 256 + t];
  Mc[t] = mc;
  Mr[t] = ws[WS_M + r * 256 + t];
  float scs = 0.f;
  #pragma unroll
  for (int rr = 0; rr < C_CL; ++rr) scs += ws[WS_CS + rr];
  __syncthreads();
  const float bpt = bp[t];
  float az = ws[WS_CS + r] * bpt;   // Z row r, col t
  float ac = scs * bpt;             // colsum(Z) col t
  #pragma unroll 8
  for (int k = 0; k < 256; ++k) {
    const float wv = Wp[(size_t)k * 256 + t];
    az += Mr[k] * wv;
    ac += Mc[k] * wv;
  }
  out[OUT_Z + r * 256 + t] = az;
  sh[t] = az + (1.f / 30.f) * ac;
  __syncthreads();
  float a1 = 0.f;
  #pragma unroll 8
  for (int k = 0; k < 256; ++k) a1 += sh[k] * W1[(size_t)k * 256 + t];
  h1out[r * 256 + t] = fmaxf(a1, 0.f);
}

// ---------------------------------------------------------------------------
// kZ2 = second Shapley layer + output head; block 30: mincut + ortho scalars
__global__ __launch_bounds__(256)
void k_z2(const float* __restrict__ ws, const float* __restrict__ W2,
          const float* __restrict__ Wo, const float* __restrict__ bo,
          float* __restrict__ out, const float vol) {
  __shared__ float sh[256];
  __shared__ float h2[256];
  __shared__ float red[4][64];
  __shared__ float wsum[4];
  const int r = blockIdx.x, t = threadIdx.x;
  if (r < C_CL) {
    float cs1 = 0.f;
    #pragma unroll
    for (int rr = 0; rr < C_CL; ++rr) cs1 += ws[WS_H1 + rr * 256 + t];
    sh[t] = ws[WS_H1 + r * 256 + t] + (1.f / 30.f) * cs1;
    __syncthreads();
    float a2 = 0.f;
    #pragma unroll 8
    for (int k = 0; k < 256; ++k) a2 += sh[k] * W2[(size_t)k * 256 + t];
    h2[t] = fmaxf(a2, 0.f);
    __syncthreads();
    const int c = t & 63, q = t >> 6;
    float ao = 0.f;
    #pragma unroll 8
    for (int k = q * 64; k < q * 64 + 64; ++k) ao += h2[k] * Wo[k * 64 + c];
    red[q][c] = ao;
    __syncthreads();
    if (t < 64)
      out[OUT_MAT + r * 64 + t] =
          bo[t] + ((red[0][t] + red[1][t]) + (red[2][t] + red[3][t]));
  } else {
    float s = 0.f;
    for (int i = t; i < 900; i += 256) {
      const float d = ws[WS_SS + i] - ((i / C_CL == i % C_CL) ? 1.f : 0.f);
      s += d * d;
    }
    #pragma unroll
    for (int m = 1; m < 64; m <<= 1) s += __shfl_xor(s, m, 64);
    if ((t & 63) == 0) wsum[t >> 6] = s;
    __syncthreads();
    if (t == 0) {
      out[OUT_OR] = sqrtf(wsum[0] + wsum[1] + wsum[2] + wsum[3]);
      out[OUT_MC] = -ws[WS_CUT] / (vol + 1e-9f);
    }
  }
}

// ---------------------------------------------------------------------------
extern "C" void kernel_launch(void* const* d_in, const int* in_sizes, int n_in,
                              void* d_out, int out_size, void* d_ws, size_t ws_size,
                              hipStream_t stream) {
  (void)n_in; (void)out_size;
  const float* x  = (const float*)d_in[0];
  const int*   ei = (const int*)d_in[1];
  const float* Wa = (const float*)d_in[2];
  const float* ba = (const float*)d_in[3];
  const float* Wp = (const float*)d_in[4];
  const float* bp = (const float*)d_in[5];
  const float* W1 = (const float*)d_in[6];
  const float* W2 = (const float*)d_in[7];
  const float* Wo = (const float*)d_in[8];
  const float* bo = (const float*)d_in[9];
  float* out = (float*)d_out;
  float* ws  = (float*)d_ws;
  unsigned* S8 = (unsigned*)(ws + WS_S8);
  float* slabs = ws + WS_SLAB0;
  const int E = in_sizes[1] / 2;

  long avail = (long)(ws_size / 4) - WS_SLAB0;
  int R = (int)(avail / SLAB_STRIDE2);
  if (R > MAX_R) R = MAX_R;
  if (R < 1) R = 1;

  k_prep<<<9, 256, 0, stream>>>(Wa, ws);
  k_node<<<1563, 256, 0, stream>>>(x, ws + WS_WT4, ba, out + OUT_S, S8);
  k_edges<<<4096, 256, 0, stream>>>(ei, E, S8, ws);
  k_M2<<<R, 256, 0, stream>>>(x, out + OUT_S, slabs, R);
  k_reduce<<<34, 256, 0, stream>>>(slabs, R, ws);
  k_z1<<<C_CL, 256, 0, stream>>>(ws, Wp, bp, W1, out, ws + WS_H1);
  k_z2<<<C_CL + 1, 256, 0, stream>>>(ws, W2, Wo, bo, out, (float)E);
}